// Round 1
// baseline (488.863 us; speedup 1.0000x reference)
//
#include <hip/hip_runtime.h>
#include <hip/hip_bf16.h>

#define NSEQ 256
#define DIM 64
#define NB 128
#define NPAIR 384
#define FINF 1e8f

using f32x4 = __attribute__((ext_vector_type(4))) float;
using s16x8 = __attribute__((ext_vector_type(8))) short;

__device__ __forceinline__ short bf16_of(float f) {
    __hip_bfloat16 h = __float2bfloat16(f);
    return __builtin_bit_cast(short, h);
}

// ---------------------------------------------------------------------------
// Kernel 1: D[p][i][j] = |a_i - b_j|^2 in bf16, row-major, one block per pair.
// a,b staged to LDS as bf16 with 16B-block XOR swizzle (conflict-free b128).
// ---------------------------------------------------------------------------
__global__ __launch_bounds__(256, 2)
void dist_kernel(const float* __restrict__ X, const float* __restrict__ Y,
                 __hip_bfloat16* __restrict__ Dout) {
    __shared__ __align__(16) short a_lds[NSEQ * DIM];
    __shared__ __align__(16) short b_lds[NSEQ * DIM];
    __shared__ float a2[NSEQ];
    __shared__ float b2[NSEQ];

    const int p = blockIdx.x;
    const int b = p & (NB - 1);
    const int g = p >> 7;  // 0: (x,y)  1: (x,x)  2: (y,y)
    const float* Arow = (g == 2 ? Y : X) + (size_t)b * NSEQ * DIM;
    const float* Brow = (g == 1 ? X : Y) + (size_t)b * NSEQ * DIM;

    const int t = threadIdx.x;
    // stage row t of A and B: 64 f32 -> 64 bf16 (swizzled), plus row sumsq
    {
        const float4* av = reinterpret_cast<const float4*>(Arow) + t * (DIM / 4);
        const float4* bv = reinterpret_cast<const float4*>(Brow) + t * (DIM / 4);
        float sa = 0.f, sb = 0.f;
#pragma unroll
        for (int q = 0; q < 8; ++q) {  // q = 16B block (8 bf16)
            float4 a0 = av[2 * q], a1 = av[2 * q + 1];
            float4 b0 = bv[2 * q], b1 = bv[2 * q + 1];
            sa += a0.x * a0.x + a0.y * a0.y + a0.z * a0.z + a0.w * a0.w
                + a1.x * a1.x + a1.y * a1.y + a1.z * a1.z + a1.w * a1.w;
            sb += b0.x * b0.x + b0.y * b0.y + b0.z * b0.z + b0.w * b0.w
                + b1.x * b1.x + b1.y * b1.y + b1.z * b1.z + b1.w * b1.w;
            s16x8 pa = { bf16_of(a0.x), bf16_of(a0.y), bf16_of(a0.z), bf16_of(a0.w),
                         bf16_of(a1.x), bf16_of(a1.y), bf16_of(a1.z), bf16_of(a1.w) };
            s16x8 pb = { bf16_of(b0.x), bf16_of(b0.y), bf16_of(b0.z), bf16_of(b0.w),
                         bf16_of(b1.x), bf16_of(b1.y), bf16_of(b1.z), bf16_of(b1.w) };
            const int off = t * DIM + ((q ^ (t & 7)) << 3);
            *reinterpret_cast<s16x8*>(&a_lds[off]) = pa;
            *reinterpret_cast<s16x8*>(&b_lds[off]) = pb;
        }
        a2[t] = sa;
        b2[t] = sb;
    }
    __syncthreads();

    const int wave = t >> 6;
    const int lane = t & 63;
    const int row0 = wave * 64;     // wave owns 64 rows x 256 cols of D
    const int lrow = lane & 15;
    const int lk   = lane >> 4;     // 0..3 (k-group)

    // All A fragments for this wave's 64 rows (4 row-tiles x 2 k-steps)
    s16x8 afr[4][2];
#pragma unroll
    for (int rt = 0; rt < 4; ++rt) {
        const int r = row0 + rt * 16 + lrow;
#pragma unroll
        for (int kk = 0; kk < 2; ++kk) {
            const int kb = kk * 4 + lk;  // 16B block index within row
            afr[rt][kk] = *reinterpret_cast<const s16x8*>(
                &a_lds[r * DIM + ((kb ^ (r & 7)) << 3)]);
        }
    }

    const size_t pbase = (size_t)p * NSEQ * NSEQ;
#pragma unroll 1
    for (int ct = 0; ct < 16; ++ct) {
        const int c = ct * 16 + lrow;
        s16x8 bfr[2];
#pragma unroll
        for (int kk = 0; kk < 2; ++kk) {
            const int kb = kk * 4 + lk;
            bfr[kk] = *reinterpret_cast<const s16x8*>(
                &b_lds[c * DIM + ((kb ^ (c & 7)) << 3)]);
        }
        const float bn = b2[c];
#pragma unroll
        for (int rt = 0; rt < 4; ++rt) {
            f32x4 acc = {0.f, 0.f, 0.f, 0.f};
            acc = __builtin_amdgcn_mfma_f32_16x16x32_bf16(afr[rt][0], bfr[0], acc, 0, 0, 0);
            acc = __builtin_amdgcn_mfma_f32_16x16x32_bf16(afr[rt][1], bfr[1], acc, 0, 0, 0);
            // C/D: col = lane&15, row = (lane>>4)*4 + j   [m89-verified]
#pragma unroll
            for (int j = 0; j < 4; ++j) {
                const int r = row0 + rt * 16 + lk * 4 + j;
                const float dist = a2[r] + bn - 2.f * acc[j];
                Dout[pbase + (size_t)r * NSEQ + c] = __float2bfloat16(dist);
            }
        }
    }
}

// ---------------------------------------------------------------------------
// Kernel 2: soft-DTW DP, one wave per pair, 4 rows per lane, all state in
// VGPRs. Per diagonal: 2 shfl_up for the row-boundary, 4 cells of softmin.
// D prefetched one diagonal-pair ahead (double-buffered dva/dvb).
// ---------------------------------------------------------------------------
__global__ __launch_bounds__(64, 1)
void dtw_kernel(const __hip_bfloat16* __restrict__ Dmat, float* __restrict__ rout) {
    const int p = blockIdx.x;
    const int L = threadIdx.x;  // lane 0..63; owns rows 4L..4L+3
    const __hip_bfloat16* Dp = Dmat + (size_t)p * NSEQ * NSEQ;

    float r1[4], r2[4];
#pragma unroll
    for (int k = 0; k < 4; ++k) { r1[k] = FINF; r2[k] = FINF; }

    float dva[4], dvb[4];

    auto loadD = [&](float* dv, int d) {
#pragma unroll
        for (int k = 0; k < 4; ++k) {
            const int i = 4 * L + k;
            const int j = d - i;
            dv[k] = (j >= 0 && j < NSEQ) ? __bfloat162float(Dp[i * NSEQ + j]) : 0.f;
        }
    };

    auto step = [&](int d, const float* dv) {
        float up1 = __shfl_up(r1[3], 1);
        float up2 = __shfl_up(r2[3], 1);
        if (L == 0) { up1 = FINF; up2 = (d == 0) ? 0.f : FINF; }
        float rn[4];
#pragma unroll
        for (int k = 0; k < 4; ++k) {
            const int i = 4 * L + k;
            const int j = d - i;
            const float a = (k == 0) ? up2 : r2[k - 1];  // R[i-1][j-1]
            const float b = (k == 0) ? up1 : r1[k - 1];  // R[i-1][j]
            const float c = r1[k];                        // R[i][j-1]
            const float m = fminf(fminf(a, b), c);
            const float e = __expf(m - a) + __expf(m - b) + __expf(m - c);
            const float sm = m - __logf(e);
            rn[k] = (j >= 0 && j < NSEQ) ? dv[k] + sm : FINF;
        }
#pragma unroll
        for (int k = 0; k < 4; ++k) { r2[k] = r1[k]; r1[k] = rn[k]; }
    };

    loadD(dva, 0);
    loadD(dvb, 1);
    for (int d = 0; d < 510; d += 2) {
        step(d, dva);
        loadD(dva, d + 2);
        step(d + 1, dvb);
        loadD(dvb, d + 3);
    }
    step(510, dva);

    if (L == 63) rout[p] = r1[3];  // R[255][255]
}

// ---------------------------------------------------------------------------
// Kernel 3: loss = mean_b( r[b] - 0.5*(r[b+128] + r[b+256]) ) + 1e-5
// ---------------------------------------------------------------------------
__global__ void reduce_kernel(const float* __restrict__ rr, float* __restrict__ out) {
    const int t = threadIdx.x;  // 128 threads
    float v = rr[t] - 0.5f * (rr[t + 128] + rr[t + 256]);
#pragma unroll
    for (int o = 32; o > 0; o >>= 1) v += __shfl_down(v, o);
    __shared__ float sred[2];
    if ((t & 63) == 0) sred[t >> 6] = v;
    __syncthreads();
    if (t == 0) out[0] = (sred[0] + sred[1]) * (1.f / 128.f) + 1e-5f;
}

extern "C" void kernel_launch(void* const* d_in, const int* in_sizes, int n_in,
                              void* d_out, int out_size, void* d_ws, size_t ws_size,
                              hipStream_t stream) {
    const float* X = (const float*)d_in[0];  // outputs (128,256,64) f32
    const float* Y = (const float*)d_in[1];  // targets (128,256,64) f32
    float* out = (float*)d_out;

    const size_t dbytes = (size_t)NPAIR * NSEQ * NSEQ * sizeof(__hip_bfloat16);  // 50,331,648
    const size_t need = dbytes + (size_t)NPAIR * sizeof(float);
    if (ws_size < need) {
        // identifiable failure sentinel: out becomes ~3.4e38
        hipMemsetAsync(d_out, 0x7f, sizeof(float), stream);
        return;
    }
    __hip_bfloat16* Dws = (__hip_bfloat16*)d_ws;
    float* rws = (float*)((char*)d_ws + dbytes);

    dist_kernel<<<NPAIR, 256, 0, stream>>>(X, Y, Dws);
    dtw_kernel<<<NPAIR, 64, 0, stream>>>(Dws, rws);
    reduce_kernel<<<1, 128, 0, stream>>>(rws, out);
}

// Round 2
// 164.571 us; speedup vs baseline: 2.9705x; 2.9705x over previous
//
#include <hip/hip_runtime.h>
#include <hip/hip_bf16.h>

#define NSEQ 256
#define DIM 64
#define NB 128
#define NPAIR 384
#define FINF 1e8f
#define LOG2E 1.4426950408889634f
#define LN2 0.6931471805599453f

using f32x4 = __attribute__((ext_vector_type(4))) float;
using s16x8 = __attribute__((ext_vector_type(8))) short;

__device__ __forceinline__ unsigned short bf16u(float f) {
    __hip_bfloat16 h = __float2bfloat16(f);
    return __builtin_bit_cast(unsigned short, h);
}
__device__ __forceinline__ short bf16s(float f) {
    __hip_bfloat16 h = __float2bfloat16(f);
    return __builtin_bit_cast(short, h);
}

// ---------------------------------------------------------------------------
// Kernel 1: D[p][i][j] = |a_i - b_j|^2, stored DIAGONAL-MAJOR:
//   S[p][(i+j) & 255][i]   (diagonals d and d+256 pack one 256-row exactly).
// One block per pair. Waves own 64-col blocks; matrix computed in 64-row
// stripes, transposed through swizzled LDS so global writes are contiguous
// 128B runs per S-row.
// ---------------------------------------------------------------------------
__global__ __launch_bounds__(256, 1)
void dist_kernel(const float* __restrict__ X, const float* __restrict__ Y,
                 unsigned short* __restrict__ S) {
    __shared__ __align__(16) short a_lds[NSEQ * DIM];
    __shared__ __align__(16) short b_lds[NSEQ * DIM];
    __shared__ float a2[NSEQ];
    __shared__ float b2[NSEQ];
    __shared__ __align__(16) unsigned short sbuf[64 * NSEQ];  // stripe, swizzled

    const int p = blockIdx.x;
    const int b = p & (NB - 1);
    const int g = p >> 7;  // 0: (x,y)  1: (x,x)  2: (y,y)
    const float* Arow = (g == 2 ? Y : X) + (size_t)b * NSEQ * DIM;
    const float* Brow = (g == 1 ? X : Y) + (size_t)b * NSEQ * DIM;

    const int t = threadIdx.x;
    // stage row t of A and B as bf16 (16B-block XOR swizzle), plus row sumsq
    {
        const float4* av = reinterpret_cast<const float4*>(Arow) + t * (DIM / 4);
        const float4* bv = reinterpret_cast<const float4*>(Brow) + t * (DIM / 4);
        float sa = 0.f, sb = 0.f;
#pragma unroll
        for (int q = 0; q < 8; ++q) {
            float4 a0 = av[2 * q], a1 = av[2 * q + 1];
            float4 b0 = bv[2 * q], b1 = bv[2 * q + 1];
            sa += a0.x * a0.x + a0.y * a0.y + a0.z * a0.z + a0.w * a0.w
                + a1.x * a1.x + a1.y * a1.y + a1.z * a1.z + a1.w * a1.w;
            sb += b0.x * b0.x + b0.y * b0.y + b0.z * b0.z + b0.w * b0.w
                + b1.x * b1.x + b1.y * b1.y + b1.z * b1.z + b1.w * b1.w;
            s16x8 pa = { bf16s(a0.x), bf16s(a0.y), bf16s(a0.z), bf16s(a0.w),
                         bf16s(a1.x), bf16s(a1.y), bf16s(a1.z), bf16s(a1.w) };
            s16x8 pb = { bf16s(b0.x), bf16s(b0.y), bf16s(b0.z), bf16s(b0.w),
                         bf16s(b1.x), bf16s(b1.y), bf16s(b1.z), bf16s(b1.w) };
            const int off = t * DIM + ((q ^ (t & 7)) << 3);
            *reinterpret_cast<s16x8*>(&a_lds[off]) = pa;
            *reinterpret_cast<s16x8*>(&b_lds[off]) = pb;
        }
        a2[t] = sa;
        b2[t] = sb;
    }
    __syncthreads();

    const int wave = t >> 6;
    const int lane = t & 63;
    const int lrow = lane & 15;
    const int lk   = lane >> 4;  // 0..3

    // B fragments: wave owns cols [64*wave, 64*wave+64)
    s16x8 bfr[4][2];
    float bn[4];
#pragma unroll
    for (int ct = 0; ct < 4; ++ct) {
        const int c = 64 * wave + ct * 16 + lrow;
#pragma unroll
        for (int kk = 0; kk < 2; ++kk) {
            const int kb = kk * 4 + lk;
            bfr[ct][kk] = *reinterpret_cast<const s16x8*>(
                &b_lds[c * DIM + ((kb ^ (c & 7)) << 3)]);
        }
        bn[ct] = b2[c];
    }

    const size_t pbase = (size_t)p * (NSEQ * NSEQ);
#pragma unroll 1
    for (int stripe = 0; stripe < 4; ++stripe) {
        const int r0 = stripe * 64;
        // A fragments for this stripe's 64 rows
        s16x8 afr[4][2];
#pragma unroll
        for (int rt = 0; rt < 4; ++rt) {
            const int r = r0 + rt * 16 + lrow;
#pragma unroll
            for (int kk = 0; kk < 2; ++kk) {
                const int kb = kk * 4 + lk;
                afr[rt][kk] = *reinterpret_cast<const s16x8*>(
                    &a_lds[r * DIM + ((kb ^ (r & 7)) << 3)]);
            }
        }
#pragma unroll
        for (int ct = 0; ct < 4; ++ct) {
            const int c = 64 * wave + ct * 16 + lrow;
#pragma unroll
            for (int rt = 0; rt < 4; ++rt) {
                f32x4 acc = {0.f, 0.f, 0.f, 0.f};
                acc = __builtin_amdgcn_mfma_f32_16x16x32_bf16(afr[rt][0], bfr[ct][0], acc, 0, 0, 0);
                acc = __builtin_amdgcn_mfma_f32_16x16x32_bf16(afr[rt][1], bfr[ct][1], acc, 0, 0, 0);
                // C/D: col = lane&15 (=lrow=c), row = lk*4 + jv  [m89-verified]
#pragma unroll
                for (int jv = 0; jv < 4; ++jv) {
                    const int rloc = rt * 16 + lk * 4 + jv;  // row within stripe
                    const float dist = a2[r0 + rloc] + bn[ct] - 2.f * acc[jv];
                    // swizzle f(row) = ((row>>2)&3)<<4, applied write & read
                    sbuf[rloc * NSEQ + (c ^ (((rloc >> 2) & 3) << 4))] = bf16u(dist);
                }
            }
        }
        __syncthreads();
        // writeout: wave handles s-rows [64*wave, 64*wave+64); per s-row this
        // stripe contributes S[s][r0 .. r0+64) = 128B contiguous.
        const int sl = lane >> 4;  // 0..3
        const int q  = lane & 15;  // 0..15
#pragma unroll
        for (int gg = 0; gg < 16; ++gg) {
            const int s = 64 * wave + gg * 4 + sl;
            unsigned int e0, e1, e2, e3;
            {
                const int il0 = 4 * q;
                const int swz = ((q & 3) << 4);  // ((il>>2)&3)<<4, il>>2 == q
                const int j0 = (s - (r0 + il0 + 0)) & 255;
                const int j1 = (s - (r0 + il0 + 1)) & 255;
                const int j2 = (s - (r0 + il0 + 2)) & 255;
                const int j3 = (s - (r0 + il0 + 3)) & 255;
                e0 = sbuf[(il0 + 0) * NSEQ + (j0 ^ swz)];
                e1 = sbuf[(il0 + 1) * NSEQ + (j1 ^ swz)];
                e2 = sbuf[(il0 + 2) * NSEQ + (j2 ^ swz)];
                e3 = sbuf[(il0 + 3) * NSEQ + (j3 ^ swz)];
            }
            uint2 w;
            w.x = e0 | (e1 << 16);
            w.y = e2 | (e3 << 16);
            *reinterpret_cast<uint2*>(&S[pbase + (size_t)s * NSEQ + r0 + 4 * q]) = w;
        }
        __syncthreads();
    }
}

// ---------------------------------------------------------------------------
// Kernel 2: soft-DTW DP. One wave per pair, 4 rows/lane, state in VGPRs.
// Diagonal d loads as ONE coalesced uint2/lane from S[d&255][4L..4L+3],
// prefetched via a 16-deep register ring. Softmin in base-2 domain
// (v_exp_f32/v_log_f32 native), R scaled by log2(e); unscale at the end.
// ---------------------------------------------------------------------------
__global__ __launch_bounds__(64, 1)
void dtw_kernel(const unsigned short* __restrict__ S, float* __restrict__ rout) {
    const int p = blockIdx.x;
    const int L = threadIdx.x;
    const unsigned short* Sp = S + (size_t)p * (NSEQ * NSEQ);
    const int i0 = 4 * L;

    float r1[4], r2[4];
#pragma unroll
    for (int k = 0; k < 4; ++k) { r1[k] = FINF; r2[k] = FINF; }

    uint2 ring[16];
#pragma unroll
    for (int u = 0; u < 16; ++u)
        ring[u] = *reinterpret_cast<const uint2*>(&Sp[u * NSEQ + i0]);

    auto step = [&](int d, uint2 w) {
        float dv[4];
        dv[0] = __builtin_bit_cast(float, w.x << 16);
        dv[1] = __builtin_bit_cast(float, w.x & 0xffff0000u);
        dv[2] = __builtin_bit_cast(float, w.y << 16);
        dv[3] = __builtin_bit_cast(float, w.y & 0xffff0000u);
        float up1 = __shfl_up(r1[3], 1);
        float up2 = __shfl_up(r2[3], 1);
        if (L == 0) { up1 = FINF; up2 = (d == 0) ? 0.f : FINF; }
        float rn[4];
#pragma unroll
        for (int k = 0; k < 4; ++k) {
            const int j = d - (i0 + k);
            const float a = (k == 0) ? up2 : r2[k - 1];   // R'[i-1][j-1]
            const float bb = (k == 0) ? up1 : r1[k - 1];  // R'[i-1][j]
            const float c = r1[k];                         // R'[i][j-1]
            const float m = fminf(fminf(a, bb), c);
            const float e = __builtin_amdgcn_exp2f(m - a)
                          + __builtin_amdgcn_exp2f(m - bb)
                          + __builtin_amdgcn_exp2f(m - c);
            const float sm = m - __builtin_amdgcn_logf(e);
            rn[k] = ((unsigned)j < 256u) ? __builtin_fmaf(dv[k], LOG2E, sm) : FINF;
        }
#pragma unroll
        for (int k = 0; k < 4; ++k) { r2[k] = r1[k]; r1[k] = rn[k]; }
    };

    int d = 0;
#pragma unroll 1
    for (int blk = 0; blk < 31; ++blk) {  // 31*16 = 496 steps
#pragma unroll
        for (int u = 0; u < 16; ++u) {
            step(d + u, ring[u]);
            ring[u] = *reinterpret_cast<const uint2*>(
                &Sp[((d + u + 16) & 255) * NSEQ + i0]);
        }
        d += 16;
    }
#pragma unroll
    for (int u = 0; u < 15; ++u) step(496 + u, ring[u]);  // d = 496..510

    if (L == 63) rout[p] = r1[3] * LN2;  // unscale from base-2 domain
}

// ---------------------------------------------------------------------------
// Kernel 3: loss = mean_b( r[b] - 0.5*(r[b+128] + r[b+256]) ) + 1e-5
// ---------------------------------------------------------------------------
__global__ void reduce_kernel(const float* __restrict__ rr, float* __restrict__ out) {
    const int t = threadIdx.x;  // 128 threads
    float v = rr[t] - 0.5f * (rr[t + 128] + rr[t + 256]);
#pragma unroll
    for (int o = 32; o > 0; o >>= 1) v += __shfl_down(v, o);
    __shared__ float sred[2];
    if ((t & 63) == 0) sred[t >> 6] = v;
    __syncthreads();
    if (t == 0) out[0] = (sred[0] + sred[1]) * (1.f / 128.f) + 1e-5f;
}

extern "C" void kernel_launch(void* const* d_in, const int* in_sizes, int n_in,
                              void* d_out, int out_size, void* d_ws, size_t ws_size,
                              hipStream_t stream) {
    const float* X = (const float*)d_in[0];  // outputs (128,256,64) f32
    const float* Y = (const float*)d_in[1];  // targets (128,256,64) f32
    float* out = (float*)d_out;

    const size_t dbytes = (size_t)NPAIR * NSEQ * NSEQ * sizeof(unsigned short);  // 50,331,648
    const size_t need = dbytes + (size_t)NPAIR * sizeof(float);
    if (ws_size < need) {
        hipMemsetAsync(d_out, 0x7f, sizeof(float), stream);  // sentinel
        return;
    }
    unsigned short* Sws = (unsigned short*)d_ws;
    float* rws = (float*)((char*)d_ws + dbytes);

    dist_kernel<<<NPAIR, 256, 0, stream>>>(X, Y, Sws);
    dtw_kernel<<<NPAIR, 64, 0, stream>>>(Sws, rws);
    reduce_kernel<<<1, 128, 0, stream>>>(rws, out);
}